// Round 4
// baseline (673.129 us; speedup 1.0000x reference)
//
#include <hip/hip_runtime.h>
#include <cstddef>

// ---------------- problem constants ----------------
#define NB 16      // batch
#define NC 256     // channels
#define NH 32
#define NW 32
#define NK 81      // 9x9 displacements

// workspace float offsets
#define WS_FG      0u                         // [16,256,32,32]
#define WS_MRES    4194304u                   // [16,81,32,32]
#define WS_SMASK   5521408u                   // [16,81,32,32]
#define WS_ANUM    6848512u                   // [16,32,32]
#define WS_CONST   6864896u                   // label[81], m[81], sw[81], step, rw, src[3], reg[3]

// fs layout for ka/kc: [c_local 32][dy 9][40 floats]  (40 = 4 halo + 32 + 4 halo)
#define FS_DY_STRIDE   40
#define FS_CH_STRIDE   360      // 9*40
#define FS_FLOATS      11520    // 32*360  (46080 B)
#define RED_STRIDE     148      // 37 quads (odd) -> bank-uniform

__device__ __forceinline__ float4 ld4(const float* p) { return *reinterpret_cast<const float4*>(p); }
__device__ __forceinline__ void st4(float* p, float4 v) { *reinterpret_cast<float4*>(p) = v; }

// XCD-aware (b,y) mapping: 512 blocks, blockIdx&7 = XCD slot -> each XCD sees 2 batches
__device__ __forceinline__ void map_by(int bi, int& b, int& y) {
    int xcd = bi & 7, slot = bi >> 3;
    b = xcd * 2 + (slot >> 5);
    y = slot & 31;
}

// ---------------- constants / distance map ----------------
__global__ void k_const(const float* lw, const float* mw, const float* sww,
                        const float* lsl, const float* fr, float* cst) {
    int tid = threadIdx.x;
    if (tid < 81) {
        int dy = tid / 9, dx = tid % 9;
        float dist = sqrtf((float)((dy - 4) * (dy - 4) + (dx - 4) * (dx - 4)));
        float lab = 0.f, mm = 0.f, ss = 0.f;
        for (int d = 0; d < 10; d++) {
            float diff = dist * 2.f - (float)d;
            float bv = (d < 9) ? fmaxf(0.f, 1.f - fabsf(diff))
                               : fminf(fmaxf(1.f + diff, 0.f), 1.f);
            lab += bv * lw[d];
            mm  += bv * mw[d];
            ss  += bv * sww[d];
        }
        cst[tid]       = lab;
        cst[81 + tid]  = 1.f / (1.f + expf(-mm));
        cst[162 + tid] = ss;
    } else if (tid == 81) {
        cst[243] = expf(lsl[0]);                                   // step_length
    } else if (tid == 82) {
        cst[244] = fmaxf(fr[0] * fr[0], 1e-10f) * (1.f / 65536.f); // reg_weight
    } else if (tid >= 83 && tid < 89) {
        cst[245 + (tid - 83)] = 0.f;                               // src[3], reg[3]
    }
}

// ---------------- copy flt input -> d_out ----------------
__global__ void k_copy(const float* __restrict__ src, float* __restrict__ dst) {
    int i = (blockIdx.x * 256 + threadIdx.x) * 4;
    st4(dst + i, ld4(src + i));
}

// Stage one 32-channel chunk of feat rows (9 dy) into fs (padded rows, halos pre-zeroed).
// 576 threads: i = tid + 576k over 2304 = 288 rows x 8 quads. Coalesced ~1KB/wave-inst.
__device__ __forceinline__ void stage_chunk(float* fs, const float* __restrict__ feat,
                                            int b, int y, int chunk, int tid) {
    const int q = tid & 7;
    const int row0 = tid >> 3;          // 0..71
    const int c0 = row0 / 9;            // 0..7
    const int dy = row0 - c0 * 9;       // fixed across iterations
    const int ry = y + dy - 4;
    if (ry >= 0 && ry < 32) {
#pragma unroll
        for (int k = 0; k < 4; k++) {
            const int c = c0 + 8 * k;   // 0..31
            float4 v = ld4(feat + ((size_t)(b * NC + chunk * 32 + c) * NH + ry) * NW + q * 4);
            st4(fs + c * FS_CH_STRIDE + dy * FS_DY_STRIDE + 4 + q * 4, v);
        }
    }
}

// Per-thread compute for one chunk: 4 channels, window from LDS (no conditionals).
__device__ __forceinline__ void compute_chunk(const float* fs, const float4* flt_s4,
                                              int chunk, int cg, int x0, int dy,
                                              float acc[9][4]) {
#pragma unroll
    for (int cc = 0; cc < 4; cc++) {
        const int cl = cg * 4 + cc;
        float4 f = flt_s4[(chunk * 32 + cl) * 8 + x0];
        const float* base = fs + cl * FS_CH_STRIDE + dy * FS_DY_STRIDE + x0 * 4;
        float4 q0 = ld4(base), q1 = ld4(base + 4), q2 = ld4(base + 8);
        float w[12] = {q0.x, q0.y, q0.z, q0.w, q1.x, q1.y, q1.z, q1.w,
                       q2.x, q2.y, q2.z, q2.w};
        float fv[4] = {f.x, f.y, f.z, f.w};
#pragma unroll
        for (int dx = 0; dx < 9; dx++)
#pragma unroll
            for (int xi = 0; xi < 4; xi++)
                acc[dx][xi] = fmaf(fv[xi], w[xi + dx], acc[dx][xi]);
    }
}

// Two-phase cross-group reduce into red (stride RED_STRIDE): groups 0-3 write, 4-7 add.
__device__ __forceinline__ void reduce_groups(float* red, int cg, int r, float acc[9][4]) {
    if (cg < 4) {
        float* row = red + r * RED_STRIDE + cg * 36;
#pragma unroll
        for (int dx = 0; dx < 9; dx++)
            st4(row + dx * 4, make_float4(acc[dx][0], acc[dx][1], acc[dx][2], acc[dx][3]));
    }
    __syncthreads();
    if (cg >= 4) {
        float* row = red + r * RED_STRIDE + (cg - 4) * 36;
#pragma unroll
        for (int dx = 0; dx < 9; dx++) {
            float4 t = ld4(row + dx * 4);
            t.x += acc[dx][0]; t.y += acc[dx][1]; t.z += acc[dx][2]; t.w += acc[dx][3];
            st4(row + dx * 4, t);
        }
    }
    __syncthreads();
}

// ---------------- KA: scores = corr(flt, feat); elementwise; mres, smask; src loss ------
// 576 threads = 8 cgroups x (9 dy x 8 xq); feat staged per 32-ch chunk in LDS.
__global__ __launch_bounds__(576) void ka_corr(const float* __restrict__ flt,
                                               const float* __restrict__ feat,
                                               const float* cst,
                                               float* __restrict__ mres,
                                               float* __restrict__ smask,
                                               float* lossacc, int it) {
    int b, y; map_by(blockIdx.x, b, y);
    const int tid = threadIdx.x;
    __shared__ float4 flt_s4[2048];     // flt row [c][xq], 32 KB
    __shared__ float pool[FS_FLOATS];   // fs during chunks; red afterwards. 45 KB

    const int cg = tid / 72, r = tid % 72;
    const int x0 = r & 7, dy = r >> 3;

    // stage flt(b,:,y,:) -> LDS ; zero fs (halos + OOB rows stay zero)
    {
        const float* base = flt + ((size_t)b * NC) * (NH * NW) + y * NW;
        for (int i = tid; i < 2048; i += 576)
            flt_s4[i] = ld4(base + (i >> 3) * (NH * NW) + (i & 7) * 4);
        const float4 z = make_float4(0.f, 0.f, 0.f, 0.f);
        for (int i = tid; i < FS_FLOATS / 4; i += 576) st4(pool + i * 4, z);
    }
    __syncthreads();

    float acc[9][4];
#pragma unroll
    for (int i = 0; i < 9; i++) { acc[i][0] = acc[i][1] = acc[i][2] = acc[i][3] = 0.f; }

    for (int chunk = 0; chunk < 8; chunk++) {
        stage_chunk(pool, feat, b, y, chunk, tid);
        __syncthreads();
        compute_chunk(pool, flt_s4, chunk, cg, x0, dy, acc);
        __syncthreads();
    }
    reduce_groups(pool, cg, r, acc);    // pool reused as red

    float srcl = 0.f;
    if (tid < 72) {
        const int x0b = tid & 7, dyb = tid >> 3;
        const float* row = pool + tid * RED_STRIDE;
#pragma unroll
        for (int dx = 0; dx < 9; dx++) {
            const int k = dyb * 9 + dx;
            const float lab = cst[k], m = cst[81 + k], sw = cst[162 + k];
            const float am = 0.5f * (1.f - m), ap = 0.5f * (1.f + m);
            float tr[4], tm[4];
#pragma unroll
            for (int xi = 0; xi < 4; xi++) {
                float s = row[dx * 4 + xi] + row[36 + dx * 4 + xi]
                        + row[72 + dx * 4 + xi] + row[108 + dx * 4 + xi];
                float act_v = am * fabsf(s) + ap * s;
                float sgn = (s > 0.f ? 1.f : 0.f) - (s < 0.f ? 1.f : 0.f);
                float msk = am * sgn + ap;
                float lres = sw * (act_v - lab);
                srcl = fmaf(lres, lres, srcl);
                tr[xi] = msk * sw * lres;
                tm[xi] = msk;
            }
            int o = ((b * NK + k) * NH + y) * NW + x0b * 4;
            st4(mres + o,  make_float4(tr[0], tr[1], tr[2], tr[3]));
            st4(smask + o, make_float4(tm[0], tm[1], tm[2], tm[3]));
        }
    }
#pragma unroll
    for (int off = 32; off > 0; off >>= 1) srcl += __shfl_down(srcl, off, 64);
    if ((tid & 63) == 0) atomicAdd(lossacc + it, srcl);
}

// ---------------- KB: fg = corr_T(mres, feat) + rw*flt; alpha_num; reg loss --------------
// 512 threads: (x0 8) x (cs 64); channels c = cc*64+cs; feat staged per-dy in LDS.
__global__ __launch_bounds__(512) void kb_grad(const float* __restrict__ flt,
                                               const float* __restrict__ feat,
                                               const float* __restrict__ mres,
                                               const float* cst,
                                               float* __restrict__ fg,
                                               float* __restrict__ anum,
                                               float* regacc, int it) {
    int b, y; map_by(blockIdx.x, b, y);
    const int tid = threadIdx.x;
    __shared__ float fs[256 * 44];      // one dy row-set, 44-float padded rows (45056 B)
    __shared__ float mres_s[81 * 32];   // mres row y (10368 B)
    __shared__ float red[32 * 65];      // alpha_num reduce (8320 B)

    const int x0 = tid & 7, cs = tid >> 3;
    const float rw = cst[244];

    // stage mres(b,:,y,:) ; zero x-halos of fs rows
    for (int i = tid; i < 648; i += 512) {
        int k = i >> 3, q = i & 7;
        float4 t = ld4(mres + ((size_t)(b * NK + k) * NH + y) * NW + q * 4);
        st4(mres_s + k * 32 + q * 4, t);
    }
    {
        const float4 z = make_float4(0.f, 0.f, 0.f, 0.f);
        int c = tid >> 1, which = tid & 1;
        st4(fs + c * 44 + (which ? 36 : 0), z);
    }

    float acc[4][4];
#pragma unroll
    for (int i = 0; i < 4; i++) { acc[i][0] = acc[i][1] = acc[i][2] = acc[i][3] = 0.f; }

    for (int dy = 0; dy < 9; dy++) {
        const int ry = y + dy - 4;
        if (ry < 0 || ry > 31) continue;            // block-uniform
        // stage feat rows for this dy: 256 ch x 32 floats, coalesced
#pragma unroll
        for (int k = 0; k < 4; k++) {
            int c = (tid >> 3) + 64 * k, q = tid & 7;
            float4 v = ld4(feat + ((size_t)(b * NC + c) * NH + ry) * NW + q * 4);
            st4(fs + c * 44 + 4 + q * 4, v);
        }
        __syncthreads();

        float rr[9][4];
#pragma unroll
        for (int dx = 0; dx < 9; dx++) {
            float4 t = ld4(mres_s + (dy * 9 + dx) * 32 + x0 * 4);
            rr[dx][0] = t.x; rr[dx][1] = t.y; rr[dx][2] = t.z; rr[dx][3] = t.w;
        }
#pragma unroll
        for (int cc = 0; cc < 4; cc++) {
            const int c = cc * 64 + cs;
            const float* base = fs + c * 44 + x0 * 4;
            float4 q0 = ld4(base), q1 = ld4(base + 4), q2 = ld4(base + 8);
            float w[12] = {q0.x, q0.y, q0.z, q0.w, q1.x, q1.y, q1.z, q1.w,
                           q2.x, q2.y, q2.z, q2.w};
#pragma unroll
            for (int dx = 0; dx < 9; dx++)
#pragma unroll
                for (int xi = 0; xi < 4; xi++)
                    acc[cc][xi] = fmaf(rr[dx][xi], w[xi + dx], acc[cc][xi]);
        }
        __syncthreads();
    }

    float regl = 0.f;
    float an[4] = {0.f, 0.f, 0.f, 0.f};
#pragma unroll
    for (int cc = 0; cc < 4; cc++) {
        int o = ((b * NC + cc * 64 + cs) * NH + y) * NW + x0 * 4;
        float4 fl = ld4(flt + o);
        float g0 = acc[cc][0] + rw * fl.x;
        float g1 = acc[cc][1] + rw * fl.y;
        float g2 = acc[cc][2] + rw * fl.z;
        float g3 = acc[cc][3] + rw * fl.w;
        st4(fg + o, make_float4(g0, g1, g2, g3));
        regl += fl.x * fl.x + fl.y * fl.y + fl.z * fl.z + fl.w * fl.w;
        an[0] += g0 * g0; an[1] += g1 * g1; an[2] += g2 * g2; an[3] += g3 * g3;
    }
#pragma unroll
    for (int xi = 0; xi < 4; xi++) red[(x0 * 4 + xi) * 65 + cs] = an[xi];
    __syncthreads();
    if (tid < 32) {
        float s = 0.f;
#pragma unroll
        for (int c2 = 0; c2 < 64; c2++) s += red[tid * 65 + c2];
        anum[(b * NH + y) * NW + tid] = s;
    }
#pragma unroll
    for (int off = 32; off > 0; off >>= 1) regl += __shfl_down(regl, off, 64);
    if ((tid & 63) == 0) atomicAdd(regacc + it, regl);
}

// ---------------- KC: sg = corr(fg, feat)*sw*mask; alpha; flt update ---------------------
__global__ __launch_bounds__(576) void kc_update(float* __restrict__ flt,
                                                 const float* __restrict__ feat,
                                                 const float* __restrict__ fg,
                                                 const float* __restrict__ smask,
                                                 const float* cst,
                                                 const float* __restrict__ anum) {
    int b, y; map_by(blockIdx.x, b, y);
    const int tid = threadIdx.x;
    __shared__ float4 flt_s4[2048];     // fg row
    __shared__ float pool[FS_FLOATS];   // fs / red / dred / alpha
    float* dred    = pool + 10656;      // after red (72*148 = 10656)
    float* alpha_s = pool + 10944;

    const int cg = tid / 72, r = tid % 72;
    const int x0 = r & 7, dy = r >> 3;

    {
        const float* base = fg + ((size_t)b * NC) * (NH * NW) + y * NW;
        for (int i = tid; i < 2048; i += 576)
            flt_s4[i] = ld4(base + (i >> 3) * (NH * NW) + (i & 7) * 4);
        const float4 z = make_float4(0.f, 0.f, 0.f, 0.f);
        for (int i = tid; i < FS_FLOATS / 4; i += 576) st4(pool + i * 4, z);
    }
    __syncthreads();

    float acc[9][4];
#pragma unroll
    for (int i = 0; i < 9; i++) { acc[i][0] = acc[i][1] = acc[i][2] = acc[i][3] = 0.f; }

    for (int chunk = 0; chunk < 8; chunk++) {
        stage_chunk(pool, feat, b, y, chunk, tid);
        __syncthreads();
        compute_chunk(pool, flt_s4, chunk, cg, x0, dy, acc);
        __syncthreads();
    }
    reduce_groups(pool, cg, r, acc);

    if (tid < 72) {
        const int x0b = tid & 7, dyb = tid >> 3;
        const float* row = pool + tid * RED_STRIDE;
        float den[4] = {0.f, 0.f, 0.f, 0.f};
#pragma unroll
        for (int dx = 0; dx < 9; dx++) {
            const int k = dyb * 9 + dx;
            const float sw = cst[162 + k];
            float4 mk = ld4(smask + ((b * NK + k) * NH + y) * NW + x0b * 4);
            float mv[4] = {mk.x, mk.y, mk.z, mk.w};
#pragma unroll
            for (int xi = 0; xi < 4; xi++) {
                float s = row[dx * 4 + xi] + row[36 + dx * 4 + xi]
                        + row[72 + dx * 4 + xi] + row[108 + dx * 4 + xi];
                float sg = sw * mv[xi] * s;
                den[xi] = fmaf(sg, sg, den[xi]);
            }
        }
#pragma unroll
        for (int xi = 0; xi < 4; xi++) dred[dyb * 32 + x0b * 4 + xi] = den[xi];
    }
    __syncthreads();
    if (tid < 32) {
        float d = 0.f;
#pragma unroll
        for (int dy2 = 0; dy2 < 9; dy2++) d += dred[dy2 * 32 + tid];
        float num = anum[(b * NH + y) * NW + tid];
        float dd = fmaxf(d + cst[244] * num, 1e-8f);
        alpha_s[tid] = cst[243] * num / dd;   // step_length * alpha
    }
    __syncthreads();

    for (int i = tid; i < 2048; i += 576) {
        int c = i >> 3, xq = i & 7;
        int o = ((b * NC + c) * NH + y) * NW + xq * 4;
        float4 fl = ld4(flt + o);
        float4 g  = flt_s4[i];   // fg row in LDS
        fl.x -= alpha_s[xq * 4 + 0] * g.x;
        fl.y -= alpha_s[xq * 4 + 1] * g.y;
        fl.z -= alpha_s[xq * 4 + 2] * g.z;
        fl.w -= alpha_s[xq * 4 + 3] * g.w;
        st4(flt + o, fl);
    }
}

// ---------------- tail: write tr, tr_src, tr_reg ----------------
__global__ void k_tail(const float* cst, float* out) {
    int i = threadIdx.x;
    if (i < 3) {
        float rw = cst[244];
        float src = 0.5f * cst[245 + i] / 16.f;
        float reg = 0.5f * rw * cst[248 + i] / 16.f;
        out[4194304 + i] = src + reg;
        out[4194307 + i] = src;
        out[4194310 + i] = reg;
    }
}

extern "C" void kernel_launch(void* const* d_in, const int* in_sizes, int n_in,
                              void* d_out, int out_size, void* d_ws, size_t ws_size,
                              hipStream_t stream) {
    (void)in_sizes; (void)n_in; (void)out_size; (void)ws_size;
    const float* flt_in = (const float*)d_in[0];
    const float* feat   = (const float*)d_in[1];
    const float* lw     = (const float*)d_in[2];
    const float* mw     = (const float*)d_in[3];
    const float* sww    = (const float*)d_in[4];
    const float* lsl    = (const float*)d_in[5];
    const float* fr     = (const float*)d_in[6];
    float* out = (float*)d_out;
    float* ws  = (float*)d_ws;

    float* fg    = ws + WS_FG;
    float* mres  = ws + WS_MRES;
    float* smask = ws + WS_SMASK;
    float* anum  = ws + WS_ANUM;
    float* cst   = ws + WS_CONST;

    k_const<<<1, 128, 0, stream>>>(lw, mw, sww, lsl, fr, cst);
    k_copy<<<4096, 256, 0, stream>>>(flt_in, out);

    for (int it = 0; it < 3; it++) {
        ka_corr<<<512, 576, 0, stream>>>(out, feat, cst, mres, smask, cst + 245, it);
        kb_grad<<<512, 512, 0, stream>>>(out, feat, mres, cst, fg, anum, cst + 248, it);
        kc_update<<<512, 576, 0, stream>>>(out, feat, fg, smask, cst, anum);
    }
    k_tail<<<1, 64, 0, stream>>>(cst, out);
}

// Round 5
// 512.853 us; speedup vs baseline: 1.3125x; 1.3125x over previous
//
#include <hip/hip_runtime.h>
#include <cstddef>

// ---------------- problem constants ----------------
#define NB 16
#define NC 256
#define NH 32
#define NW 32
#define NK 81

// LDS float offsets (total 36,608 floats = 146,432 B, 1 block/CU)
#define L_FLT    0        // [256][36]  flt row, padded stride 36
#define L_FG     9216     // [256][36]  filter-grad row
#define L_MRES   18432    // [81][32]   mapped residuals row (C reuses as sg^2 scratch)
#define L_SMASK  21024    // [81][32]
#define L_FS     23616    // A/C: [32 ch][9 dy][44]; B: [256 ch][44]; red: [4][2592]; part: [128][33]
#define L_CL     36288    // cst copy [245]
#define L_ANUM   36544    // [32]
#define L_ALPHA  36576    // [32]
#define L_TOTAL  36608

__device__ __forceinline__ float4 ld4(const float* p) { return *reinterpret_cast<const float4*>(p); }
__device__ __forceinline__ void st4(float* p, float4 v) { *reinterpret_cast<float4*>(p) = v; }

__device__ __forceinline__ void map_by(int bi, int& b, int& y) {
    int xcd = bi & 7, slot = bi >> 3;
    b = xcd * 2 + (slot >> 5);
    y = slot & 31;
}

// ---------------- constants / distance map ----------------
__global__ void k_const(const float* lw, const float* mw, const float* sww,
                        const float* lsl, const float* fr, float* cst) {
    int tid = threadIdx.x;
    if (tid < 81) {
        int dy = tid / 9, dx = tid % 9;
        float dist = sqrtf((float)((dy - 4) * (dy - 4) + (dx - 4) * (dx - 4)));
        float lab = 0.f, mm = 0.f, ss = 0.f;
        for (int d = 0; d < 10; d++) {
            float diff = dist * 2.f - (float)d;
            float bv = (d < 9) ? fmaxf(0.f, 1.f - fabsf(diff))
                               : fminf(fmaxf(1.f + diff, 0.f), 1.f);
            lab += bv * lw[d];
            mm  += bv * mw[d];
            ss  += bv * sww[d];
        }
        cst[tid]       = lab;
        cst[81 + tid]  = 1.f / (1.f + expf(-mm));
        cst[162 + tid] = ss;
    } else if (tid == 81) {
        cst[243] = expf(lsl[0]);
    } else if (tid == 82) {
        cst[244] = fmaxf(fr[0] * fr[0], 1e-10f) * (1.f / 65536.f);
    } else if (tid >= 83 && tid < 89) {
        cst[245 + (tid - 83)] = 0.f;
    }
}

// Correlation pass: scores(k,x) = sum_c A[c,x]*featpad[c,y+dy,x+dx-4]
// Results left in 4 red buffers at S[L_FS + p*2592], consumer sums the 4.
// Mapping: lg=tid/36 (16 groups, 2 ch each per 32-ch chunk), r36: oct=r36&3 (8-px), dyA=r36>>2.
__device__ __forceinline__ void corr_pass(float* S, const float* __restrict__ feat,
                                          int a_off, int b, int y, int tid,
                                          int lg, int oct, int dyA,
                                          int qs, int c0s, int dys, bool vst, int rys) {
    float* fs = S + L_FS;
    const float4 z4 = make_float4(0.f, 0.f, 0.f, 0.f);
    for (int i = tid; i < 12672 / 4; i += 576) st4(fs + i * 4, z4);
    __syncthreads();

    float acc[9][8];
#pragma unroll
    for (int dx = 0; dx < 9; dx++)
#pragma unroll
        for (int i = 0; i < 8; i++) acc[dx][i] = 0.f;

    const float* gbase = feat + (((size_t)b * NC) * NH + rys) * NW + qs * 4;
    float4 R[4];
    if (vst) {
#pragma unroll
        for (int k2 = 0; k2 < 4; k2++)
            R[k2] = ld4(gbase + (size_t)(c0s + 8 * k2) * (NH * NW));
    }
#pragma unroll 1
    for (int chunk = 0; chunk < 8; chunk++) {
        if (vst) {
#pragma unroll
            for (int k2 = 0; k2 < 4; k2++)
                st4(fs + (c0s + 8 * k2) * 396 + dys * 44 + 4 + qs * 4, R[k2]);
        }
        __syncthreads();
        if (chunk < 7 && vst) {
#pragma unroll
            for (int k2 = 0; k2 < 4; k2++)
                R[k2] = ld4(gbase + (size_t)((chunk + 1) * 32 + c0s + 8 * k2) * (NH * NW));
        }
#pragma unroll
        for (int j = 0; j < 2; j++) {
            const int cl = lg * 2 + j;
            const float* wb = fs + cl * 396 + dyA * 44 + oct * 8;
            float4 w0 = ld4(wb), w1 = ld4(wb + 4), w2 = ld4(wb + 8), w3 = ld4(wb + 12);
            float w[16] = {w0.x, w0.y, w0.z, w0.w, w1.x, w1.y, w1.z, w1.w,
                           w2.x, w2.y, w2.z, w2.w, w3.x, w3.y, w3.z, w3.w};
            const float* fb = S + a_off + (chunk * 32 + cl) * 36 + oct * 8;
            float4 f0 = ld4(fb), f1 = ld4(fb + 4);
            float f[8] = {f0.x, f0.y, f0.z, f0.w, f1.x, f1.y, f1.z, f1.w};
#pragma unroll
            for (int dx = 0; dx < 9; dx++)
#pragma unroll
                for (int i = 0; i < 8; i++)
                    acc[dx][i] = fmaf(f[i], w[i + dx], acc[dx][i]);
        }
        __syncthreads();
    }
    // 4-buffer, 4-phase cross-group reduce (16 logical groups -> 4 buffers)
#pragma unroll 1
    for (int p = 0; p < 4; p++) {
        if ((lg >> 2) == p) {
            float* B = fs + (lg & 3) * 2592;
#pragma unroll
            for (int dx = 0; dx < 9; dx++) {
                int idx = (dyA * 9 + dx) * 32 + oct * 8;
                if (p == 0) {
                    st4(B + idx,     make_float4(acc[dx][0], acc[dx][1], acc[dx][2], acc[dx][3]));
                    st4(B + idx + 4, make_float4(acc[dx][4], acc[dx][5], acc[dx][6], acc[dx][7]));
                } else {
                    float4 t0 = ld4(B + idx), t1 = ld4(B + idx + 4);
                    t0.x += acc[dx][0]; t0.y += acc[dx][1]; t0.z += acc[dx][2]; t0.w += acc[dx][3];
                    t1.x += acc[dx][4]; t1.y += acc[dx][5]; t1.z += acc[dx][6]; t1.w += acc[dx][7];
                    st4(B + idx, t0); st4(B + idx + 4, t1);
                }
            }
        }
        __syncthreads();
    }
}

// ---------------- mega kernel: one block = one (b,y) row, all 3 iterations ----------------
__global__ __launch_bounds__(576, 2) void mega(const float* __restrict__ flt_in,
                                               const float* __restrict__ feat,
                                               float* __restrict__ out,
                                               float* __restrict__ cst_g) {
    __shared__ float S[L_TOTAL];
    int b, y; map_by(blockIdx.x, b, y);
    const int tid = threadIdx.x;

    // A/C compute mapping
    const int lg  = tid / 36;
    const int r36 = tid - lg * 36;
    const int oct = r36 & 3;
    const int dyA = r36 >> 2;
    // staging mapping (A/C chunks)
    const int qs  = tid & 7;
    const int rs  = tid >> 3;
    const int c0s = rs / 9;
    const int dys = rs - c0s * 9;
    const int rys = y + dys - 4;
    const bool vst = (rys >= 0 && rys < 32);
    // B mapping
    const int octB = tid & 3, cs = tid >> 2;
    const bool actB = (cs < 128);

    // stage constants + flt row
    for (int i = tid; i < 245; i += 576) S[L_CL + i] = cst_g[i];
    {
        const float* base = flt_in + ((size_t)b * NC * NH + y) * NW;
        for (int i = tid; i < 2048; i += 576) {
            int c = i >> 3, q = i & 7;
            st4(S + L_FLT + c * 36 + q * 4, ld4(base + c * (NH * NW) + q * 4));
        }
    }
    __syncthreads();
    const float step = S[L_CL + 243];
    const float rw   = S[L_CL + 244];

#pragma unroll 1
    for (int it = 0; it < 3; it++) {
        // ---------- pass A: scores = corr(flt), elementwise -> mres/smask, src loss ----------
        corr_pass(S, feat, L_FLT, b, y, tid, lg, oct, dyA, qs, c0s, dys, vst, rys);

        float srcl = 0.f;
        if (tid < 324) {
            const int kk = tid >> 2, o8 = (tid & 3) * 8;
            const int base = kk * 32 + o8;
            const float lab = S[L_CL + kk], m = S[L_CL + 81 + kk], sw = S[L_CL + 162 + kk];
            const float am = 0.5f * (1.f - m), ap = 0.5f * (1.f + m);
#pragma unroll
            for (int h = 0; h < 2; h++) {
                float4 s0 = ld4(S + L_FS + base + h * 4);
                float4 s1 = ld4(S + L_FS + 2592 + base + h * 4);
                float4 s2 = ld4(S + L_FS + 5184 + base + h * 4);
                float4 s3 = ld4(S + L_FS + 7776 + base + h * 4);
                float sv[4] = {s0.x + s1.x + s2.x + s3.x, s0.y + s1.y + s2.y + s3.y,
                               s0.z + s1.z + s2.z + s3.z, s0.w + s1.w + s2.w + s3.w};
                float tr[4], tm[4];
#pragma unroll
                for (int xi = 0; xi < 4; xi++) {
                    float s = sv[xi];
                    float act = am * fabsf(s) + ap * s;
                    float sgn = (s > 0.f ? 1.f : 0.f) - (s < 0.f ? 1.f : 0.f);
                    float msk = am * sgn + ap;
                    float lres = sw * (act - lab);
                    srcl = fmaf(lres, lres, srcl);
                    tr[xi] = msk * sw * lres;
                    tm[xi] = msk;
                }
                st4(S + L_MRES + base + h * 4,  make_float4(tr[0], tr[1], tr[2], tr[3]));
                st4(S + L_SMASK + base + h * 4, make_float4(tm[0], tm[1], tm[2], tm[3]));
            }
        }
#pragma unroll
        for (int off = 32; off > 0; off >>= 1) srcl += __shfl_down(srcl, off, 64);
        if ((tid & 63) == 0) atomicAdd(cst_g + 245 + it, srcl);
        __syncthreads();

        // ---------- pass B: fg = corr_T(mres) + rw*flt; alpha_num; reg loss ----------
        {
            // zero x-halos of B layout [256][44]: quads 0 and 9 of each row
            const float4 z4 = make_float4(0.f, 0.f, 0.f, 0.f);
            for (int i = tid; i < 512; i += 576) {
                int c = i >> 1, h = i & 1;
                st4(S + L_FS + c * 44 + (h ? 36 : 0), z4);
            }
            float accb[2][8];
#pragma unroll
            for (int j = 0; j < 2; j++)
#pragma unroll
                for (int i = 0; i < 8; i++) accb[j][i] = 0.f;

#pragma unroll 1
            for (int dy = 0; dy < 9; dy++) {
                const int ry = y + dy - 4;
                if (ry < 0 || ry >= 32) continue;        // block-uniform
                __syncthreads();                          // prior reads/compute done
                for (int i = tid; i < 2048; i += 576) {
                    int c = i >> 3, q = i & 7;
                    st4(S + L_FS + c * 44 + 4 + q * 4,
                        ld4(feat + (((size_t)(b * NC + c)) * NH + ry) * NW + q * 4));
                }
                __syncthreads();
                if (actB) {
                    float rr[9][8];
#pragma unroll
                    for (int dx = 0; dx < 9; dx++) {
                        int mi = (dy * 9 + dx) * 32 + octB * 8;
                        float4 t0 = ld4(S + L_MRES + mi), t1 = ld4(S + L_MRES + mi + 4);
                        rr[dx][0] = t0.x; rr[dx][1] = t0.y; rr[dx][2] = t0.z; rr[dx][3] = t0.w;
                        rr[dx][4] = t1.x; rr[dx][5] = t1.y; rr[dx][6] = t1.z; rr[dx][7] = t1.w;
                    }
#pragma unroll
                    for (int j = 0; j < 2; j++) {
                        const int c = cs * 2 + j;
                        const float* wb = S + L_FS + c * 44 + octB * 8;
                        float4 w0 = ld4(wb), w1 = ld4(wb + 4), w2 = ld4(wb + 8), w3 = ld4(wb + 12);
                        float w[16] = {w0.x, w0.y, w0.z, w0.w, w1.x, w1.y, w1.z, w1.w,
                                       w2.x, w2.y, w2.z, w2.w, w3.x, w3.y, w3.z, w3.w};
#pragma unroll
                        for (int dx = 0; dx < 9; dx++)
#pragma unroll
                            for (int i = 0; i < 8; i++)
                                accb[j][i] = fmaf(rr[dx][i], w[i + dx], accb[j][i]);
                    }
                }
            }
            __syncthreads();   // fs free; fg/anum phase

            float regl = 0.f;
            if (actB) {
                float g[2][8];
#pragma unroll
                for (int j = 0; j < 2; j++) {
                    const int c = cs * 2 + j;
                    const float* fb = S + L_FLT + c * 36 + octB * 8;
                    float4 f0 = ld4(fb), f1 = ld4(fb + 4);
                    float fv[8] = {f0.x, f0.y, f0.z, f0.w, f1.x, f1.y, f1.z, f1.w};
#pragma unroll
                    for (int i = 0; i < 8; i++) {
                        g[j][i] = accb[j][i] + rw * fv[i];
                        regl = fmaf(fv[i], fv[i], regl);
                    }
                    st4(S + L_FG + c * 36 + octB * 8,
                        make_float4(g[j][0], g[j][1], g[j][2], g[j][3]));
                    st4(S + L_FG + c * 36 + octB * 8 + 4,
                        make_float4(g[j][4], g[j][5], g[j][6], g[j][7]));
                }
#pragma unroll
                for (int i = 0; i < 8; i++)
                    S[L_FS + cs * 33 + octB * 8 + i] = g[0][i] * g[0][i] + g[1][i] * g[1][i];
            }
#pragma unroll
            for (int off = 32; off > 0; off >>= 1) regl += __shfl_down(regl, off, 64);
            if ((tid & 63) == 0) atomicAdd(cst_g + 248 + it, regl);
            __syncthreads();
            if (tid < 32) {
                float s = 0.f;
                for (int c2 = 0; c2 < 128; c2++) s += S[L_FS + c2 * 33 + tid];
                S[L_ANUM + tid] = s;
            }
            __syncthreads();
        }

        // ---------- pass C: sg = corr(fg)*sw*mask; alpha; flt update ----------
        corr_pass(S, feat, L_FG, b, y, tid, lg, oct, dyA, qs, c0s, dys, vst, rys);

        if (tid < 324) {
            const int kk = tid >> 2, o8 = (tid & 3) * 8;
            const int base = kk * 32 + o8;
            const float sw = S[L_CL + 162 + kk];
#pragma unroll
            for (int h = 0; h < 2; h++) {
                float4 s0 = ld4(S + L_FS + base + h * 4);
                float4 s1 = ld4(S + L_FS + 2592 + base + h * 4);
                float4 s2 = ld4(S + L_FS + 5184 + base + h * 4);
                float4 s3 = ld4(S + L_FS + 7776 + base + h * 4);
                float4 mk = ld4(S + L_SMASK + base + h * 4);
                float sg0 = sw * mk.x * (s0.x + s1.x + s2.x + s3.x);
                float sg1 = sw * mk.y * (s0.y + s1.y + s2.y + s3.y);
                float sg2 = sw * mk.z * (s0.z + s1.z + s2.z + s3.z);
                float sg3 = sw * mk.w * (s0.w + s1.w + s2.w + s3.w);
                st4(S + L_MRES + base + h * 4,   // mres dead -> sg^2 scratch
                    make_float4(sg0 * sg0, sg1 * sg1, sg2 * sg2, sg3 * sg3));
            }
        }
        __syncthreads();
        if (tid < 32) {
            float den = 0.f;
            for (int k = 0; k < 81; k++) den += S[L_MRES + k * 32 + tid];
            float num = S[L_ANUM + tid];
            float dd = fmaxf(den + rw * num, 1e-8f);
            S[L_ALPHA + tid] = step * num / dd;
        }
        __syncthreads();
        for (int i = tid; i < 2048; i += 576) {
            int c = i >> 3, q = i & 7;
            float* fp = S + L_FLT + c * 36 + q * 4;
            float4 fl = ld4(fp);
            float4 g = ld4(S + L_FG + c * 36 + q * 4);
            fl.x -= S[L_ALPHA + q * 4 + 0] * g.x;
            fl.y -= S[L_ALPHA + q * 4 + 1] * g.y;
            fl.z -= S[L_ALPHA + q * 4 + 2] * g.z;
            fl.w -= S[L_ALPHA + q * 4 + 3] * g.w;
            st4(fp, fl);
        }
        __syncthreads();
    }

    // final: write flt row to output
    for (int i = tid; i < 2048; i += 576) {
        int c = i >> 3, q = i & 7;
        st4(out + ((size_t)(b * NC + c) * NH + y) * NW + q * 4,
            ld4(S + L_FLT + c * 36 + q * 4));
    }
}

// ---------------- tail: write tr, tr_src, tr_reg ----------------
__global__ void k_tail(const float* cst, float* out) {
    int i = threadIdx.x;
    if (i < 3) {
        float rw = cst[244];
        float src = 0.5f * cst[245 + i] / 16.f;
        float reg = 0.5f * rw * cst[248 + i] / 16.f;
        out[4194304 + i] = src + reg;
        out[4194307 + i] = src;
        out[4194310 + i] = reg;
    }
}

extern "C" void kernel_launch(void* const* d_in, const int* in_sizes, int n_in,
                              void* d_out, int out_size, void* d_ws, size_t ws_size,
                              hipStream_t stream) {
    (void)in_sizes; (void)n_in; (void)out_size; (void)ws_size;
    const float* flt_in = (const float*)d_in[0];
    const float* feat   = (const float*)d_in[1];
    const float* lw     = (const float*)d_in[2];
    const float* mw     = (const float*)d_in[3];
    const float* sww    = (const float*)d_in[4];
    const float* lsl    = (const float*)d_in[5];
    const float* fr     = (const float*)d_in[6];
    float* out = (float*)d_out;
    float* cst = (float*)d_ws;

    k_const<<<1, 128, 0, stream>>>(lw, mw, sww, lsl, fr, cst);
    mega<<<512, 576, 0, stream>>>(flt_in, feat, out, cst);
    k_tail<<<1, 64, 0, stream>>>(cst, out);
}